// Round 20
// baseline (102.581 us; speedup 1.0000x reference)
//
#include <hip/hip_runtime.h>
#include <math.h>

typedef _Float16 half8 __attribute__((ext_vector_type(8)));
typedef __fp16   fp16x2 __attribute__((ext_vector_type(2)));  // cvt_pkrtz's return type
typedef float f32x4 __attribute__((ext_vector_type(4)));

// Branchless exact-grade GELU: x*0.5*(1+erf(x/sqrt(2))) with A&S 7.1.26 erf,
// |erf err| <= 1.5e-7 (vs output threshold 2.47e-2).
__device__ __forceinline__ float gelu_f(float v) {
    float y  = v * 0.70710678118654752f;
    float ay = __builtin_fabsf(y);
    float t  = __builtin_amdgcn_rcpf(__builtin_fmaf(0.3275911f, ay, 1.0f));
    float p  = __builtin_fmaf(t, 1.061405429f, -1.453152027f);
    p = __builtin_fmaf(p, t, 1.421413741f);
    p = __builtin_fmaf(p, t, -0.284496736f);
    p = __builtin_fmaf(p, t, 0.254829592f);
    p = p * t;
    float e  = __builtin_amdgcn_exp2f(ay * ay * -1.4426950408889634f);
    float er = __builtin_fmaf(-p, e, 1.0f);        // erf(|y|), saturates to 1
    er = __builtin_copysignf(er, v);               // restore sign
    float hv = 0.5f * v;
    return __builtin_fmaf(hv, er, hv);
}

// Sum over the 16 lanes of a DPP row (our c index) via row_ror rotate-reduce.
// Pure VALU -- replaces __shfl_xor's ds_swizzle (LDS pipe) with DPP adds.
// Verified numerically in r14 (absmax 0.0078).
__device__ __forceinline__ float rowsum16(float v) {
    int t;
    t = __builtin_amdgcn_update_dpp(0, __float_as_int(v), 0x121, 0xf, 0xf, true); // ror:1
    v += __int_as_float(t);
    t = __builtin_amdgcn_update_dpp(0, __float_as_int(v), 0x122, 0xf, 0xf, true); // ror:2
    v += __int_as_float(t);
    t = __builtin_amdgcn_update_dpp(0, __float_as_int(v), 0x124, 0xf, 0xf, true); // ror:4
    v += __int_as_float(t);
    t = __builtin_amdgcn_update_dpp(0, __float_as_int(v), 0x128, 0xf, 0xf, true); // ror:8
    v += __int_as_float(t);
    return v;
}

#define MFMA16(A, B, C) __builtin_amdgcn_mfma_f32_16x16x32_f16((A), (B), (C), 0, 0, 0)

// One wave owns a 16-row tile end-to-end.  fp16 MFMA, fp32 accum.
// A-frag: row = lane&15, k = 32*s + 8*(lane>>4) + j.  C-layout (m89):
// col = lane&15, row = 4*(lane>>4) + reg.
//
// Ledger through r19: occupancy 4/5/6 waves/SIMD flat at 97-100us; coalesced
// loads flat; pipelining/forced-pins/fence-removal all regress.  Remaining
// suspect: the LDS pipe -- per tile, 12 wtab b128 reads + 24 staging writes +
// 5 reads + 16 ds_swizzle shuffles ~ 430-450 pipe-cycles ~ 46us/CU of
// service time, a per-CU shared unit (explains occupancy insensitivity).
// This round, TWO surgical LDS cuts on the r10 body (DS/tile 57 -> 33):
//  (1) epilogue shuffles -> DPP row_ror rotate-reduce (VALU pipe),
//  (2) the 8 gamma-free W1 frags (s=1,2) hoisted to regs pre-loop
//      (+32 VGPR -> ~116, under the proven (256,4)=128 cap; explicit
//      pre-loop reads are immune to the in-loop "memory" clobbers).
__global__ __launch_bounds__(256, 4) void mlp_mfma_kernel(
    const float* __restrict__ x,
    const float* __restrict__ alpha,
    const float* __restrict__ beta,
    const float* __restrict__ gamma,
    const float* __restrict__ gscal,
    const float* __restrict__ W1, const float* __restrict__ b1,
    const float* __restrict__ W2, const float* __restrict__ b2,
    const float* __restrict__ Wres, const float* __restrict__ bres,
    const float* __restrict__ W6, const float* __restrict__ b6,
    float* __restrict__ out, int B)
{
    const int lane = threadIdx.x & 63;
    const int wid  = threadIdx.x >> 6;
    const int c    = lane & 15;   // col (N) index / A-row index
    const int g    = lane >> 4;   // k-group 0..3

    // Weight-fragment table (block-shared): frags 0..11 = W1[t*3+s],
    // 12..15 = W2[12+t*2+s], 16..17 = Wres[16+t].  18 frags x 64 lanes x 16B.
    __shared__ __align__(16) _Float16 wtab[18 * 512];
    // per-wave activation staging (no cross-wave sharing) -- r10 layout
    __shared__ __align__(16) _Float16 h1buf[4][16 * 72];
    __shared__ __align__(16) _Float16 h2buf[4][16 * 40];
    _Float16* __restrict__ h1b = h1buf[wid];
    _Float16* __restrict__ h2b = h2buf[wid];

    // ---- build weight tables once (wave 0) ----
    if (wid == 0) {
        float gm[8];
        #pragma unroll
        for (int j = 0; j < 8; ++j) {
            int k  = 8 * g + j;
            int kc = k < 3 ? 3 : (k > 22 ? 22 : k);     // clamp: safe load
            float gv = gamma[kc];
            gm[j] = (k >= 3 && k < 23) ? gv : 1.0f;
        }
        #pragma unroll
        for (int t = 0; t < 4; ++t)
            #pragma unroll
            for (int s = 0; s < 3; ++s)
                #pragma unroll
                for (int j = 0; j < 8; ++j) {
                    int k  = 32 * s + 8 * g + j;
                    int kc = k < 73 ? k : 72;           // clamp: no OOB load
                    float v = W1[(16 * t + c) * 73 + kc];
                    if (s == 0) v *= gm[j];             // gamma folded into s=0
                    wtab[(t * 3 + s) * 512 + lane * 8 + j] =
                        (k < 73) ? (_Float16)v : (_Float16)0.f;
                }
        #pragma unroll
        for (int t = 0; t < 2; ++t)
            #pragma unroll
            for (int s = 0; s < 2; ++s)
                #pragma unroll
                for (int j = 0; j < 8; ++j)
                    wtab[(12 + t * 2 + s) * 512 + lane * 8 + j] =
                        (_Float16)W2[(16 * t + c) * 64 + 32 * s + 8 * g + j];
        #pragma unroll
        for (int t = 0; t < 2; ++t)
            #pragma unroll
            for (int j = 0; j < 8; ++j)
                wtab[(16 + t) * 512 + lane * 8 + j] =
                    (_Float16)Wres[(16 * t + c) * 32 + 8 * g + j];
    }

    // biases / final weights stay in registers (10 regs)
    float b1f[4], b2f[2], brf[2], w6f[2];
    #pragma unroll
    for (int t = 0; t < 4; ++t) b1f[t] = b1[16 * t + c];
    #pragma unroll
    for (int t = 0; t < 2; ++t) { b2f[t] = b2[16 * t + c]; brf[t] = bres[16 * t + c]; w6f[t] = W6[16 * t + c]; }
    const float b6g = b6[0] + gscal[0];

    __syncthreads();   // table visible to all waves (once, outside hot loop)

    const _Float16* wt = wtab + lane * 8;   // shared vaddr; frag f at +f*512

    // ---- HOIST: gamma-free W1 frags (s=1,2) to registers, read ONCE ----
    // (explicit pre-loop reads; register values survive the in-loop clobbers)
    half8 w1h[4][2];
    #pragma unroll
    for (int t = 0; t < 4; ++t) {
        w1h[t][0] = *reinterpret_cast<const half8*>(wt + (t * 3 + 1) * 512);
        w1h[t][1] = *reinterpret_cast<const half8*>(wt + (t * 3 + 2) * 512);
    }

    const int ntiles = B >> 4;
    const int totw   = gridDim.x * 4;
    for (int tile = blockIdx.x * 4 + wid; tile < ntiles; tile += totw) {
        const int R0 = tile << 4;
        const float* __restrict__ xr = x + (size_t)(R0 + c) * 73;

        // ---- x loads (issued up front) ----
        float xv0[8], xv1[8], xv2[8];
        #pragma unroll
        for (int j = 0; j < 8; ++j) xv0[j] = xr[8 * g + j];
        #pragma unroll
        for (int j = 0; j < 8; ++j) xv1[j] = xr[32 + 8 * g + j];
        #pragma unroll
        for (int j = 0; j < 8; ++j) {
            int k = 64 + 8 * g + j;
            float v = xr[k < 73 ? k : 72];
            xv2[j] = (k < 73) ? v : 0.f;
        }

        // embed gathers (only g==0 lanes own cols 0/1); consumed by the LAST
        // k-step's MFMAs
        float xa = 0.f, xb = 0.f;
        if (g == 0) {
            xa = alpha[(int)xv0[0]];
            xb = beta[(int)xv0[1]];
        }

        // ---- layer 1: 73->64.  k-steps 1,2 first (frags in regs now) ----
        union H8 { half8 h8; fp16x2 h2[4]; };
        H8 a1u, a2u;
        #pragma unroll
        for (int j = 0; j < 4; ++j) {
            a1u.h2[j] = __builtin_amdgcn_cvt_pkrtz(xv1[2 * j], xv1[2 * j + 1]);
            a2u.h2[j] = __builtin_amdgcn_cvt_pkrtz(xv2[2 * j], xv2[2 * j + 1]);
        }
        f32x4 acc[4];
        #pragma unroll
        for (int t = 0; t < 4; ++t) { f32x4 z = { b1f[t], b1f[t], b1f[t], b1f[t] }; acc[t] = z; }
        #pragma unroll
        for (int t = 0; t < 4; ++t) acc[t] = MFMA16(a1u.h8, w1h[t][0], acc[t]);
        #pragma unroll
        for (int t = 0; t < 4; ++t) acc[t] = MFMA16(a2u.h8, w1h[t][1], acc[t]);

        // k-step 0 last: gamma pre-folded in wtab s=0; cols 0/1 = embeds
        H8 a0u;
        #pragma unroll
        for (int j = 0; j < 4; ++j)
            a0u.h2[j] = __builtin_amdgcn_cvt_pkrtz(xv0[2 * j], xv0[2 * j + 1]);
        {
            fp16x2 we = __builtin_amdgcn_cvt_pkrtz(xa, xb);
            if (g == 0) a0u.h2[0] = we;
        }
        #pragma unroll
        for (int t = 0; t < 4; ++t)
            acc[t] = MFMA16(a0u.h8,
                            *reinterpret_cast<const half8*>(wt + (t * 3 + 0) * 512),
                            acc[t]);

        // GELU -> h1 to LDS (row = 4g+r, col = 16t+c, stride 72)
        #pragma unroll
        for (int t = 0; t < 4; ++t)
            #pragma unroll
            for (int r = 0; r < 4; ++r)
                h1b[(4 * g + r) * 72 + 16 * t + c] = (_Float16)gelu_f(acc[t][r]);

        asm volatile("s_waitcnt lgkmcnt(0)" ::: "memory");

        // ---- layer 2: 64->32 ----
        half8 w2f[2][2];
        #pragma unroll
        for (int t = 0; t < 2; ++t)
            #pragma unroll
            for (int s = 0; s < 2; ++s)
                w2f[t][s] = *reinterpret_cast<const half8*>(wt + (12 + t * 2 + s) * 512);

        half8 a2f0 = *reinterpret_cast<const half8*>(&h1b[c * 72 + 8 * g]);
        half8 a2f1 = *reinterpret_cast<const half8*>(&h1b[c * 72 + 32 + 8 * g]);
        f32x4 ac2[2];
        #pragma unroll
        for (int t = 0; t < 2; ++t) {
            f32x4 z = { b2f[t], b2f[t], b2f[t], b2f[t] };
            z = MFMA16(a2f0, w2f[t][0], z);
            ac2[t] = MFMA16(a2f1, w2f[t][1], z);
        }
        float h2c[2][4];
        #pragma unroll
        for (int t = 0; t < 2; ++t)
            #pragma unroll
            for (int r = 0; r < 4; ++r)
                h2c[t][r] = gelu_f(ac2[t][r]);

        // h2 to LDS (stride 40)
        #pragma unroll
        for (int t = 0; t < 2; ++t)
            #pragma unroll
            for (int r = 0; r < 4; ++r)
                h2b[(4 * g + r) * 40 + 16 * t + c] = (_Float16)h2c[t][r];

        asm volatile("s_waitcnt lgkmcnt(0)" ::: "memory");

        // ---- residual layer: C-init = bres + h2 (matching C-layout slots) ----
        half8 wrf[2];
        #pragma unroll
        for (int t = 0; t < 2; ++t)
            wrf[t] = *reinterpret_cast<const half8*>(wt + (16 + t) * 512);

        half8 arf = *reinterpret_cast<const half8*>(&h2b[c * 40 + 8 * g]);
        f32x4 acr[2];
        #pragma unroll
        for (int t = 0; t < 2; ++t) {
            f32x4 z = { brf[t] + h2c[t][0], brf[t] + h2c[t][1],
                        brf[t] + h2c[t][2], brf[t] + h2c[t][3] };
            acr[t] = MFMA16(arf, wrf[t], z);
        }

        // ---- final 32->1: per-lane partial, DPP rotate-reduce over c ----
        f32x4 p;
        #pragma unroll
        for (int r = 0; r < 4; ++r)
            p[r] = rowsum16(gelu_f(acr[0][r]) * w6f[0] + gelu_f(acr[1][r]) * w6f[1]);
        if (c == 0) {
            f32x4 o = { p[0] + b6g, p[1] + b6g, p[2] + b6g, p[3] + b6g };
            *reinterpret_cast<f32x4*>(out + R0 + 4 * g) = o;  // rows R0+4g..+3
        }
    }
}

extern "C" void kernel_launch(void* const* d_in, const int* in_sizes, int n_in,
                              void* d_out, int out_size, void* d_ws, size_t ws_size,
                              hipStream_t stream) {
    const float* x     = (const float*)d_in[0];
    const float* alpha = (const float*)d_in[1];
    const float* beta  = (const float*)d_in[2];
    const float* gamma = (const float*)d_in[3];
    const float* g     = (const float*)d_in[4];
    const float* W1    = (const float*)d_in[5];
    const float* b1    = (const float*)d_in[6];
    const float* W2    = (const float*)d_in[7];
    const float* b2    = (const float*)d_in[8];
    const float* Wres  = (const float*)d_in[9];
    const float* bres  = (const float*)d_in[10];
    const float* W6    = (const float*)d_in[11];
    const float* b6    = (const float*)d_in[12];
    float* out = (float*)d_out;

    int B = out_size;          // 1e6 rows; divisible by 16
    // 1024 blocks = 4 blocks/CU (r10's proven residency).  Occupancy is
    // closed as a lever (4/5/6 waves/SIMD all flat); this round cuts the
    // LDS pipe instead.
    int nblocks = 1024;
    mlp_mfma_kernel<<<nblocks, 256, 0, stream>>>(x, alpha, beta, gamma, g,
                                                 W1, b1, W2, b2, Wres, bres,
                                                 W6, b6, out, B);
}